// Round 11
// baseline (219.169 us; speedup 1.0000x reference)
//
#include <hip/hip_runtime.h>
#include <math.h>

#define BATCH 256
#define QL 50
#define EMB 50
#define DL 2000
#define NB 11
#define SEG 20
#define RPB 100      // d rows per block (DL/SEG)
#define TPB 256
#define RSTRIDE 52   // LDS row stride in floats: 208 B -> float4-aligned rows
#define HB (QL * NB) // 550
#define HW 138       // packed hist words (552 B, covers 550 bytes)
#define HSTR 552     // per-segment global hist stride in bytes

// ---- 5q x 4r register tile ----
#define FOR_M5(M) M(0) M(1) M(2) M(3) M(4)
#define FOR_N4(M) M(0) M(1) M(2) M(3)
#define FOR_MN(M) \
  M(0,0) M(0,1) M(0,2) M(0,3) \
  M(1,0) M(1,1) M(1,2) M(1,3) \
  M(2,0) M(2,1) M(2,2) M(2,3) \
  M(3,0) M(3,1) M(3,2) M(3,3) \
  M(4,0) M(4,1) M(4,2) M(4,3)

#define DECL_ACC(m,n) float a_##m##_##n = 0.f;
#define DB(n)  const float* db##n = s_d + (g + (n) * 25) * RSTRIDE;
#define LQ(m)  const float4 qv##m = *(const float4*)(qb0 + (m) * RSTRIDE + o);
#define LD(n)  const float4 dv##n = *(const float4*)(db##n + o);
#define LQ2(m) const float2 qt##m = *(const float2*)(qb0 + (m) * RSTRIDE + 48);
#define LD2(n) const float2 dt##n = *(const float2*)(db##n + 48);
// e-ascending exact chain: quads k=0..11 (e=0..47), then tail e=48,49
#define FMA4(m,n) \
  a_##m##_##n = fmaf(qv##m.x, dv##n.x, a_##m##_##n); \
  a_##m##_##n = fmaf(qv##m.y, dv##n.y, a_##m##_##n); \
  a_##m##_##n = fmaf(qv##m.z, dv##n.z, a_##m##_##n); \
  a_##m##_##n = fmaf(qv##m.w, dv##n.w, a_##m##_##n);
#define FMA2T(m,n) \
  a_##m##_##n = fmaf(qt##m.x, dt##n.x, a_##m##_##n); \
  a_##m##_##n = fmaf(qt##m.y, dt##n.y, a_##m##_##n);
// binning verbatim ((a*qrn)*drn, trunc, clamp); validity = sign bit; fabsf exact
#define HIST_MN(m,n) if (qs##m > 0.f && ds##n > 0.f) { \
    const float s_  = a_##m##_##n * qs##m * ds##n; \
    const float tt_ = ((s_ + 1.000001f) * 0.5f) * 10.0f; \
    int bb_ = (int)tt_; bb_ = bb_ < 0 ? 0 : (bb_ > 10 ? 10 : bb_); \
    const int hidx_ = (qg5 + (m)) * NB + bb_; \
    atomicAdd(&s_hist[hidx_ >> 2], 1u << ((hidx_ & 3) * 8)); }

// ---------------- sim+hist (+gate on seg==0) ----------------
__global__ __launch_bounds__(TPB, 5)
void sim_hist_kernel(const float* __restrict__ de,
                     const int*   __restrict__ did,
                     const float* __restrict__ qe,
                     const int*   __restrict__ qid,
                     const float* __restrict__ Wg,
                     unsigned char* __restrict__ g_hist, // [B][SEG][HSTR]
                     float* __restrict__ gate,
                     int* __restrict__ cnt)
{
    const int bid = blockIdx.x;
    const int b   = bid / SEG;
    const int seg = bid - b * SEG;
    const int t   = threadIdx.x;

    __shared__ __align__(16) float s_d[RPB * RSTRIDE]; // 20,800 B
    __shared__ __align__(16) float s_q[QL * RSTRIDE];  // 10,400 B
    __shared__ float    s_drn[RPB];                    //    400 B (sign=validity)
    __shared__ float    s_qrn[QL];                     //    200 B (sign=validity)
    __shared__ unsigned s_hist[HW];                    //    552 B byte-packed
    __shared__ float    r2s[4];                        // total 32,368 -> 32,768

    if (bid == 0 && t == 0) *cnt = 0;      // re-arm epilogue flag each launch
    for (int i = t; i < HW; i += TPB) s_hist[i] = 0u;

    // ---- coalesced staging: both tiles are contiguous float2 ranges ----
    const float2* dsrc = (const float2*)(de + ((size_t)b * DL + seg * RPB) * EMB);
    for (int i = t; i < RPB * 25; i += TPB) {
        const int r = i / 25, ep = i - r * 25;
        ((float2*)(s_d + r * RSTRIDE))[ep] = dsrc[i];
    }
    const float2* qsrc = (const float2*)(qe + (size_t)b * QL * EMB);
    for (int i = t; i < QL * 25; i += TPB) {
        const int r = i / 25, ep = i - r * 25;
        ((float2*)(s_q + r * RSTRIDE))[ep] = qsrc[i];
    }
    __syncthreads();

    // ---- norms from LDS (identical bits), exact e-ascending fmaf chains ----
    if (t < RPB) {
        const float2* row = (const float2*)(s_d + t * RSTRIDE);
        float ss = 0.f;
        #pragma unroll
        for (int ep = 0; ep < 25; ++ep) {
            const float2 v = row[ep];
            ss = fmaf(v.x, v.x, ss);
            ss = fmaf(v.y, v.y, ss);
        }
        const float rn = 1.0f / (sqrtf(ss) + 1e-8f);
        s_drn[t] = (did[(size_t)b * DL + seg * RPB + t] > 0) ? rn : -rn;
    } else if (t >= 128 && t < 128 + QL) {
        const int j = t - 128;
        const float2* row = (const float2*)(s_q + j * RSTRIDE);
        float ss = 0.f;
        #pragma unroll
        for (int ep = 0; ep < 25; ++ep) {
            const float2 v = row[ep];
            ss = fmaf(v.x, v.x, ss);
            ss = fmaf(v.y, v.y, ss);
        }
        const float rn = 1.0f / (sqrtf(ss) + 1e-8f);
        s_qrn[j] = (qid[(size_t)b * QL + j] > 0) ? rn : -rn;
    }
    __syncthreads();

    // ---- 5x4 register-tiled dot products, b128 LDS reads ----
    if (t < 250) {
        const int qg5 = (t % 10) * 5;      // q rows qg5..qg5+4
        const int g   = t / 10;            // d rows g, g+25, g+50, g+75
        const float* qb0 = s_q + qg5 * RSTRIDE;
        FOR_N4(DB)
        FOR_MN(DECL_ACC)
        #pragma unroll 1
        for (int k = 0; k < 12; ++k) {     // rolled: live set ~70 VGPR, no hoist
            const int o = 4 * k;
            FOR_M5(LQ)
            FOR_N4(LD)
            FOR_MN(FMA4)                   // 80 fmacs per 9 ds_read_b128
        }
        {                                  // tail e = 48,49
            FOR_M5(LQ2)
            FOR_N4(LD2)
            FOR_MN(FMA2T)
        }
        const float qs0 = s_qrn[qg5+0], qs1 = s_qrn[qg5+1], qs2 = s_qrn[qg5+2],
                    qs3 = s_qrn[qg5+3], qs4 = s_qrn[qg5+4];
        const float ds0 = s_drn[g], ds1 = s_drn[g+25],
                    ds2 = s_drn[g+50], ds3 = s_drn[g+75];
        FOR_MN(HIST_MN)                    // 20 packed-byte LDS atomics
    }
    __syncthreads();

    // ---- flush block-private packed hist (word copy; byte layout == u8 hist) ----
    unsigned* hout = (unsigned*)(g_hist + ((size_t)b * SEG + seg) * HSTR);
    for (int i = t; i < HW; i += TPB) hout[i] = s_hist[i];

    // ---- gate dot (seg==0 only; verbatim exact code, passed R6/R8/R9) ----
    if (seg == 0) {
        const float* qbase = qe + (size_t)b * QL * EMB;
        float a2 = 0.f;
        for (int i = t; i < QL * EMB; i += TPB)
            a2 = fmaf(qbase[i], Wg[i], a2);
        #pragma unroll
        for (int off = 32; off > 0; off >>= 1) a2 += __shfl_down(a2, off, 64);
        if ((t & 63) == 0) r2s[t >> 6] = a2;
        __syncthreads();
        if (t == 0) gate[b] = r2s[0] + r2s[1] + r2s[2] + r2s[3];
    }
}

// ---------------- ffn + (last block) softmax/score ----------------
__global__ __launch_bounds__(TPB)
void ffn_score_kernel(const unsigned char* __restrict__ g_hist,
                      const float* __restrict__ W1,
                      const float* __restrict__ bias,
                      const float* __restrict__ gate,
                      float* __restrict__ ffn,
                      int* __restrict__ cnt,
                      float* __restrict__ out)
{
    const int b = blockIdx.x;
    const int t = threadIdx.x;
    const unsigned char* hb = g_hist + (size_t)b * SEG * HSTR;

    float a1 = 0.f;
    for (int i = t; i < HB; i += TPB) {
        unsigned c = 0;
        #pragma unroll
        for (int s = 0; s < SEG; ++s) c += hb[s * HSTR + i];  // integer: exact
        a1 = fmaf(logf((float)c + 1e-5f), W1[i], a1);
    }
    #pragma unroll
    for (int off = 32; off > 0; off >>= 1) a1 += __shfl_down(a1, off, 64);
    __shared__ float r1s[4];
    __shared__ int   s_last;
    if ((t & 63) == 0) r1s[t >> 6] = a1;
    __syncthreads();
    if (t == 0) {
        const float v = r1s[0] + r1s[1] + r1s[2] + r1s[3] + bias[0];
        atomicExch(&ffn[b], v);            // device-coherent publish
        __threadfence();
        const int old = atomicAdd(cnt, 1);
        s_last = (old == BATCH - 1) ? 1 : 0;
    }
    __syncthreads();
    if (!s_last) return;
    __threadfence();

    // ---- score: verbatim exact softmax-over-batch path ----
    __shared__ float buf[4];
    __shared__ float sM, sZ, sS;
    const float g = gate[t];
    const float f = atomicAdd(&ffn[t], 0.0f);      // device-coherent read

    float m = g;
    #pragma unroll
    for (int off = 32; off > 0; off >>= 1) m = fmaxf(m, __shfl_down(m, off, 64));
    if ((t & 63) == 0) buf[t >> 6] = m;
    __syncthreads();
    if (t == 0) sM = fmaxf(fmaxf(buf[0], buf[1]), fmaxf(buf[2], buf[3]));
    __syncthreads();

    const float e = expf(g - sM);
    float z = e;
    #pragma unroll
    for (int off = 32; off > 0; off >>= 1) z += __shfl_down(z, off, 64);
    __syncthreads();
    if ((t & 63) == 0) buf[t >> 6] = z;
    __syncthreads();
    if (t == 0) sZ = buf[0] + buf[1] + buf[2] + buf[3];
    __syncthreads();

    const float p = e / sZ;
    float s = p;
    #pragma unroll
    for (int off = 32; off > 0; off >>= 1) s += __shfl_down(s, off, 64);
    __syncthreads();
    if ((t & 63) == 0) buf[t >> 6] = s;
    __syncthreads();
    if (t == 0) sS = buf[0] + buf[1] + buf[2] + buf[3];
    __syncthreads();

    out[t] = f * sS;
}

// ---------------- launcher: 2 dispatches ----------------
extern "C" void kernel_launch(void* const* d_in, const int* in_sizes, int n_in,
                              void* d_out, int out_size, void* d_ws, size_t ws_size,
                              hipStream_t stream)
{
    const float* qe  = (const float*)d_in[0];
    const float* de  = (const float*)d_in[1];
    const float* W1  = (const float*)d_in[2];
    const float* b1  = (const float*)d_in[3];
    const float* Wg  = (const float*)d_in[4];
    const int*   qid = (const int*)d_in[5];
    const int*   did = (const int*)d_in[6];
    float* out = (float*)d_out;

    // workspace (~2.83 MB)
    char* ws = (char*)d_ws;
    unsigned char* g_hist = (unsigned char*)ws;        // 256*20*552 = 2,826,240 B
    float* gate = (float*)(ws + 2826240);              // 1,024 B
    float* ffn  = gate + BATCH;                        // 1,024 B
    int*   cnt  = (int*)(ffn + BATCH);                 // 4 B

    sim_hist_kernel<<<BATCH * SEG, TPB, 0, stream>>>(de, did, qe, qid, Wg,
                                                     g_hist, gate, cnt);
    ffn_score_kernel<<<BATCH, TPB, 0, stream>>>(g_hist, W1, b1, gate, ffn, cnt, out);
}